// Round 13
// baseline (75.713 us; speedup 1.0000x reference)
//
#include <hip/hip_runtime.h>

typedef __attribute__((ext_vector_type(8))) short short8;
typedef __attribute__((ext_vector_type(4))) float f32x4;

#define EPS   1e-3f
#define ALPHA 0.3f
#define PS    (10 * 1024 * 16)   // Mp plane stride (elements)

#define MFMA(a, b, c) __builtin_amdgcn_mfma_f32_16x16x32_bf16((a), (b), (c), 0, 0, 0)

__device__ __forceinline__ unsigned short f2bf(float f) {
    unsigned u = __float_as_uint(f);
    unsigned r = u + 0x7FFFu + ((u >> 16) & 1u);
    return (unsigned short)(r >> 16);
}
__device__ __forceinline__ float bf2f(unsigned short u) {
    return __uint_as_float((unsigned)u << 16);
}
__device__ __forceinline__ float lrelu(float v) { return v > 0.f ? v : ALPHA * v; }

// ---------------------------------------------------------------------------
// Split-K M partial: block (xt,yt) writes its k-slice contribution of
// M = h@Wd (+bd on plane 0) to its own bf16 plane Mp[yt] — plain stores.
// Mp layout: [yt][k10][1024 rows][16] (d-contiguous).
// ---------------------------------------------------------------------------
__device__ __forceinline__ void m_splitk(
    const unsigned short (*Hb)[40], const unsigned short (*WdT)[40],
    const float* __restrict__ bd, unsigned short* __restrict__ Mp,
    int xt, int yt, int t)
{
    const int lane = t & 63, w = t >> 6, r = lane & 15, g = lane >> 4;
    unsigned short* plane = Mp + (size_t)yt * PS;
    for (int tt = w; tt < 14; tt += 4) {
        const int rt = tt / 7, c7 = tt % 7;
        const short8 a = *(const short8*)&Hb[rt * 16 + r][g * 8];
        const short8 b = *(const short8*)&WdT[c7 * 16 + r][g * 8];
        f32x4 acc = {0.f, 0.f, 0.f, 0.f};
        acc = MFMA(a, b, acc);
        const int c = c7 * 16 + r;
        if (c < 100) {
            const int k10 = c / 10, d = c - k10 * 10;
            const float bv = (yt == 0) ? bd[c] : 0.f;
            unsigned short* dst = plane + (size_t)k10 * (1024 * 16)
                                + (size_t)(xt * 32 + rt * 16 + g * 4) * 16 + d;
#pragma unroll
            for (int i = 0; i < 4; ++i) dst[(size_t)i * 16] = f2bf(acc[i] + bv);
        }
    }
}

// ---------------------------------------------------------------------------
// N1: h0 = x@W0 + b0 (grid 32x8) + Mp0 split-K partial.
// ---------------------------------------------------------------------------
__global__ __launch_bounds__(256) void h0_kernel(
    const float* __restrict__ x, const float* __restrict__ W0,
    const float* __restrict__ b0,
    const float* __restrict__ Wd0, const float* __restrict__ bd0,
    float* __restrict__ h0, unsigned short* __restrict__ Mp0)
{
    __shared__ unsigned short At[32][520];
    __shared__ unsigned short Bt[32][520];
    __shared__ unsigned short Hb[32][40];
    __shared__ unsigned short WdT[112][40];

    const int t = threadIdx.x, xt = blockIdx.x, yt = blockIdx.y;

    // A stage: x rows -> bf16
    {
        const int row = t >> 3, kc = t & 7;
        const float* xp = x + (size_t)(xt * 32 + row) * 512 + kc * 64;
#pragma unroll
        for (int i = 0; i < 8; ++i) {
            const float4 lo = ((const float4*)xp)[i * 2];
            const float4 hi = ((const float4*)xp)[i * 2 + 1];
            short8 p;
            p[0] = f2bf(lo.x); p[1] = f2bf(lo.y); p[2] = f2bf(lo.z); p[3] = f2bf(lo.w);
            p[4] = f2bf(hi.x); p[5] = f2bf(hi.y); p[6] = f2bf(hi.z); p[7] = f2bf(hi.w);
            *(short8*)&At[row][kc * 64 + i * 8] = p;
        }
    }
    // B stage: W0 col-tile transposed
    {
        const int kr = t >> 3, nf = t & 7;
#pragma unroll
        for (int rnd = 0; rnd < 16; ++rnd) {
            const int k = kr + rnd * 32;
            const float4 v = *(const float4*)&W0[(size_t)k * 256 + yt * 32 + nf * 4];
            Bt[nf * 4 + 0][k] = f2bf(v.x);
            Bt[nf * 4 + 1][k] = f2bf(v.y);
            Bt[nf * 4 + 2][k] = f2bf(v.z);
            Bt[nf * 4 + 3][k] = f2bf(v.w);
        }
    }
    // WdT stage: Wd0 k-rows [yt*32,+32), cols padded to 112
    for (int idx = t; idx < 112 * 32; idx += 256) {
        const int kk = idx / 112, c = idx - kk * 112;
        WdT[c][kk] = (c < 100) ? f2bf(Wd0[(size_t)(yt * 32 + kk) * 100 + c])
                               : (unsigned short)0;
    }
    __syncthreads();

    const int lane = t & 63, w = t >> 6;
    const int wr = w >> 1, wn = w & 1, r = lane & 15, g = lane >> 4;
    const unsigned short* Ap = &At[wr * 16 + r][g * 8];
    const unsigned short* Bp = &Bt[wn * 16 + r][g * 8];
    f32x4 a0 = {0.f, 0.f, 0.f, 0.f}, a1 = {0.f, 0.f, 0.f, 0.f};
#pragma unroll
    for (int k0 = 0; k0 < 512; k0 += 64) {
        a0 = MFMA(*(const short8*)(Ap + k0),      *(const short8*)(Bp + k0),      a0);
        a1 = MFMA(*(const short8*)(Ap + k0 + 32), *(const short8*)(Bp + k0 + 32), a1);
    }
    const f32x4 acc = a0 + a1;
    const int bcol = yt * 32 + wn * 16 + r;
    const float bv = b0[bcol];
    const int orow = xt * 32 + wr * 16 + g * 4;
    const int lrow = wr * 16 + g * 4;
#pragma unroll
    for (int i = 0; i < 4; ++i) {
        const float hv = acc[i] + bv;
        h0[(size_t)(orow + i) * 256 + bcol] = hv;
        Hb[lrow + i][wn * 16 + r] = f2bf(hv);
    }
    __syncthreads();

    m_splitk(Hb, WdT, bd0, Mp0, xt, yt, t);
}

// ---------------------------------------------------------------------------
// N2/N4: diversity over summed partial planes. grid (32,10). No fences.
// Ms[1024][16] fp32 = sum of 8 bf16 planes (bias in plane 0).
// ---------------------------------------------------------------------------
__global__ __launch_bounds__(256) void div_kernel(
    const unsigned short* __restrict__ Mp, float* __restrict__ divOut)
{
    __shared__ float Ms[1024 * 16];
    __shared__ float red[256];

    const int t = threadIdx.x, rt = blockIdx.x, k = blockIdx.y;

    const unsigned short* base = Mp + (size_t)k * (1024 * 16);
    for (int ch = t; ch < 2048; ch += 256) {          // ushort8 chunks
        float s[8] = {0.f, 0.f, 0.f, 0.f, 0.f, 0.f, 0.f, 0.f};
#pragma unroll
        for (int yt = 0; yt < 8; ++yt) {
            const short8 v = *(const short8*)(base + (size_t)yt * PS + ch * 8);
#pragma unroll
            for (int j = 0; j < 8; ++j) s[j] += bf2f((unsigned short)v[j]);
        }
#pragma unroll
        for (int j = 0; j < 8; ++j) Ms[ch * 8 + j] = s[j];
    }
    __syncthreads();

    const int il = t & 31, jc = t >> 5;
    const int i = rt * 32 + il;
    const float4 m0 = *(const float4*)&Ms[i * 16];
    const float4 m1 = *(const float4*)&Ms[i * 16 + 4];
    const float2 m2 = *(const float2*)&Ms[i * 16 + 8];

    float acc = 0.f;
    const int jB = jc * 128;
#pragma unroll 2
    for (int j = jB; j < jB + 128; ++j) {
        const float4 v0 = *(const float4*)&Ms[j * 16];
        const float4 v1 = *(const float4*)&Ms[j * 16 + 4];
        const float2 v2 = *(const float2*)&Ms[j * 16 + 8];
        float l1 = fabsf(m0.x - v0.x) + fabsf(m0.y - v0.y)
                 + fabsf(m0.z - v0.z) + fabsf(m0.w - v0.w)
                 + fabsf(m1.x - v1.x) + fabsf(m1.y - v1.y)
                 + fabsf(m1.z - v1.z) + fabsf(m1.w - v1.w)
                 + fabsf(m2.x - v2.x) + fabsf(m2.y - v2.y);
        acc += __expf(-l1);
    }

    red[t] = acc;
    __syncthreads();
    if (t < 32) {
        float s = 0.f;
#pragma unroll
        for (int c = 0; c < 8; ++c) s += red[c * 32 + t];
        divOut[(size_t)(rt * 32 + t) * 10 + k] = s;
    }
}

// ---------------------------------------------------------------------------
// N3: LN0 (fused, x8 redundant — R10-validated) + h1 = a0@W1 + b1 (grid 32x8)
// + Mp1 split-K partial.
// ---------------------------------------------------------------------------
__global__ __launch_bounds__(256) void h1_kernel(
    const float* __restrict__ h0, const float* __restrict__ div0,
    const float* __restrict__ beta0,
    const float* __restrict__ W1, const float* __restrict__ b1,
    const float* __restrict__ Wd1, const float* __restrict__ bd1,
    float* __restrict__ h1, unsigned short* __restrict__ Mp1)
{
    __shared__ unsigned short At[32][296];
    __shared__ unsigned short Bt[32][296];
    __shared__ unsigned short Hb[32][40];
    __shared__ unsigned short WdT[112][40];

    const int t = threadIdx.x, xt = blockIdx.x, yt = blockIdx.y;
    const int lane = t & 63, w = t >> 6;

    // B stage: W1 col-tile transposed, k >= 266 zero (K padded to 288)
    {
        const int kr = t >> 3, nf = t & 7;
#pragma unroll
        for (int rnd = 0; rnd < 9; ++rnd) {
            const int k = kr + rnd * 32;
            float4 v = make_float4(0.f, 0.f, 0.f, 0.f);
            if (k < 266) v = *(const float4*)&W1[(size_t)k * 256 + yt * 32 + nf * 4];
            Bt[nf * 4 + 0][k] = f2bf(v.x);
            Bt[nf * 4 + 1][k] = f2bf(v.y);
            Bt[nf * 4 + 2][k] = f2bf(v.z);
            Bt[nf * 4 + 3][k] = f2bf(v.w);
        }
    }
    // WdT stage
    for (int idx = t; idx < 112 * 32; idx += 256) {
        const int kk = idx / 112, c = idx - kk * 112;
        WdT[c][kk] = (c < 100) ? f2bf(Wd1[(size_t)(yt * 32 + kk) * 100 + c])
                               : (unsigned short)0;
    }

    // LN0: wave w handles rows w*8 .. w*8+7
    for (int rr = 0; rr < 8; ++rr) {
        const int row = xt * 32 + w * 8 + rr;
        const float4 hv = ((const float4*)(h0 + (size_t)row * 256))[lane];
        const float dvv = (lane < 10) ? div0[(size_t)row * 10 + lane] : 0.f;
        float s = hv.x + hv.y + hv.z + hv.w + dvv;
        float q = hv.x * hv.x + hv.y * hv.y + hv.z * hv.z + hv.w * hv.w + dvv * dvv;
#pragma unroll
        for (int m = 32; m > 0; m >>= 1) { s += __shfl_xor(s, m); q += __shfl_xor(q, m); }
        const float mean = s * (1.f / 266.f);
        const float var  = q * (1.f / 266.f) - mean * mean;
        const float inv  = rsqrtf(var + EPS);
        const int lr = w * 8 + rr;
        const float4 b4 = ((const float4*)beta0)[lane];
        ushort4 o;
        o.x = f2bf(lrelu((hv.x - mean) * inv + b4.x));
        o.y = f2bf(lrelu((hv.y - mean) * inv + b4.y));
        o.z = f2bf(lrelu((hv.z - mean) * inv + b4.z));
        o.w = f2bf(lrelu((hv.w - mean) * inv + b4.w));
        *(ushort4*)&At[lr][lane * 4] = o;
        if (lane < 10)
            At[lr][256 + lane] = f2bf(lrelu((dvv - mean) * inv + beta0[256 + lane]));
        else if (lane < 40)
            At[lr][256 + lane] = 0;   // pad 266..295
    }
    __syncthreads();

    // MFMA K=288
    const int wr = w >> 1, wn = w & 1, r = lane & 15, g = lane >> 4;
    const unsigned short* Ap = &At[wr * 16 + r][g * 8];
    const unsigned short* Bp = &Bt[wn * 16 + r][g * 8];
    f32x4 a0 = {0.f, 0.f, 0.f, 0.f}, a1 = {0.f, 0.f, 0.f, 0.f};
#pragma unroll
    for (int k0 = 0; k0 < 256; k0 += 64) {
        a0 = MFMA(*(const short8*)(Ap + k0),      *(const short8*)(Bp + k0),      a0);
        a1 = MFMA(*(const short8*)(Ap + k0 + 32), *(const short8*)(Bp + k0 + 32), a1);
    }
    a0 = MFMA(*(const short8*)(Ap + 256), *(const short8*)(Bp + 256), a0);
    const f32x4 acc = a0 + a1;
    const int bcol = yt * 32 + wn * 16 + r;
    const float bv = b1[bcol];
    const int orow = xt * 32 + wr * 16 + g * 4;
    const int lrow = wr * 16 + g * 4;
#pragma unroll
    for (int i = 0; i < 4; ++i) {
        const float hv = acc[i] + bv;
        h1[(size_t)(orow + i) * 256 + bcol] = hv;
        Hb[lrow + i][wn * 16 + r] = f2bf(hv);
    }
    __syncthreads();

    m_splitk(Hb, WdT, bd1, Mp1, xt, yt, t);
}

// ---------------------------------------------------------------------------
// N5: LN1 + LeakyReLU + dot(Wf) + bf. 256 blocks x 4 waves, one row per wave.
// ---------------------------------------------------------------------------
__global__ __launch_bounds__(256) void ln_final(
    const float* __restrict__ h1, const float* __restrict__ div1,
    const float* __restrict__ beta1, const float* __restrict__ Wf,
    const float* __restrict__ bf, float* __restrict__ out)
{
    const int t = threadIdx.x, lane = t & 63;
    const int row = blockIdx.x * 4 + (t >> 6);

    const float4 hv = ((const float4*)(h1 + (size_t)row * 256))[lane];
    const float dv = (lane < 10) ? div1[(size_t)row * 10 + lane] : 0.f;

    float s = hv.x + hv.y + hv.z + hv.w + dv;
    float q = hv.x * hv.x + hv.y * hv.y + hv.z * hv.z + hv.w * hv.w + dv * dv;
#pragma unroll
    for (int m = 32; m > 0; m >>= 1) { s += __shfl_xor(s, m); q += __shfl_xor(q, m); }

    const float mean = s * (1.f / 266.f);
    const float var  = q * (1.f / 266.f) - mean * mean;
    const float inv  = rsqrtf(var + EPS);

    const float4 bv = ((const float4*)beta1)[lane];
    const float4 wf = ((const float4*)Wf)[lane];
    float d = lrelu((hv.x - mean) * inv + bv.x) * wf.x
            + lrelu((hv.y - mean) * inv + bv.y) * wf.y
            + lrelu((hv.z - mean) * inv + bv.z) * wf.z
            + lrelu((hv.w - mean) * inv + bv.w) * wf.w;
    if (lane < 10)
        d += lrelu((dv - mean) * inv + beta1[256 + lane]) * Wf[256 + lane];
#pragma unroll
    for (int m = 32; m > 0; m >>= 1) d += __shfl_xor(d, m);
    if (lane == 0) out[row] = d + bf[0];
}

// ---------------------------------------------------------------------------
extern "C" void kernel_launch(void* const* d_in, const int* in_sizes, int n_in,
                              void* d_out, int out_size, void* d_ws, size_t ws_size,
                              hipStream_t stream)
{
    const float* x     = (const float*)d_in[0];
    const float* W0    = (const float*)d_in[1];
    const float* b0    = (const float*)d_in[2];
    const float* Wd0   = (const float*)d_in[3];
    const float* bd0   = (const float*)d_in[4];
    const float* beta0 = (const float*)d_in[5];
    const float* W1    = (const float*)d_in[6];
    const float* b1    = (const float*)d_in[7];
    const float* Wd1   = (const float*)d_in[8];
    const float* bd1   = (const float*)d_in[9];
    const float* beta1 = (const float*)d_in[10];
    const float* Wf    = (const float*)d_in[11];
    const float* bf    = (const float*)d_in[12];
    float* out = (float*)d_out;

    float* fws = (float*)d_ws;
    float* h0   = fws;                      // 1024*256 fp32
    float* h1   = h0 + 1024 * 256;          // 1024*256 fp32
    float* div0 = h1 + 1024 * 256;          // 1024*10
    float* div1 = div0 + 1024 * 10;         // 1024*10
    unsigned short* Mp0 = (unsigned short*)(div1 + 1024 * 10);  // 8 planes x PS
    unsigned short* Mp1 = Mp0 + 8 * PS;                         // 8 planes x PS

    dim3 blk(256);

    // N1: h0 = x@W0+b0, Mp0 partials
    h0_kernel<<<dim3(32, 8), blk, 0, stream>>>(x, W0, b0, Wd0, bd0, h0, Mp0);

    // N2: diversity 0 (sums Mp0 planes)
    div_kernel<<<dim3(32, 10), blk, 0, stream>>>(Mp0, div0);

    // N3: LN0 (fused) + h1 = a0@W1+b1, Mp1 partials
    h1_kernel<<<dim3(32, 8), blk, 0, stream>>>(
        h0, div0, beta0, W1, b1, Wd1, bd1, h1, Mp1);

    // N4: diversity 1 (sums Mp1 planes)
    div_kernel<<<dim3(32, 10), blk, 0, stream>>>(Mp1, div1);

    // N5: LN1 + head
    ln_final<<<dim3(256), blk, 0, stream>>>(h1, div1, beta1, Wf, bf, out);
}